// Round 10
// baseline (599.368 us; speedup 1.0000x reference)
//
#include <hip/hip_runtime.h>
#include <stdint.h>

// TopoSignature via parallel Boruvka MST. Round 10: one dispatch per round.
// Each round_k block REPLICATES the previous round's hook (O(N) root-level
// work in LDS: raw hook -> in-place 2-cycle resolve -> 12 pointer jumps),
// then scans with self-computed labels. No threadfence/ticket (round-8's
// failure): cross-round state is parity ping-ponged (best, comp) and best
// keys carry a round tag in the top byte so stale entries always lose
// atomicMin and hooks reject them — kernel boundaries are the only fence.
// Block 0 (per matrix) materializes comp/edges/ncomp for the next dispatch.
// Dispatches: 27 -> 15. scanA: asm memory barrier pins the 16-load batch.

#define N        4096
#define NROUNDS  12

typedef unsigned long long u64;
typedef uint32_t u32;
typedef unsigned short u16;

#define INFK (~0ull)

struct Ws {
    u64 best[2][2][N];    // [matrix][round parity][slot], tagged keys:
                          // ((13-r)<<56)|(wbits<<24)|(lo<<12)|hi
    u32 comp[2][2][N];    // [matrix][round parity][vertex]
    u32 edges[2][N];      // edge per dying root, (lo<<12)|hi; (i<<12)|i sentinel
    u32 ncomp[2];
    u32 pad[14];
    u32 bmw[2][N * 64];   // per-row per-lane-block bound: weight bits (0xFFFFFFFF = inf)
    u16 bmc[2][N * 64];   // per-row per-lane-block bound: column
};   // ~3.4 MB — smaller than the 4.33 MB proven to fit in rounds 6-9

__device__ __forceinline__ u64 umin64(u64 a, u64 b) { return a < b ? a : b; }
__device__ __forceinline__ u64 shfl_xor_u64(u64 x, int off) {
    u32 lo = (u32)x, hi = (u32)(x >> 32);
    lo = (u32)__shfl_xor((int)lo, off, 64);
    hi = (u32)__shfl_xor((int)hi, off, 64);
    return ((u64)hi << 32) | lo;
}

// ---- round 0: full scan, one wave/row, lane-private block minima ----
// Lane L owns cols {4L+q+256j}. asm barrier keeps all 16 loads in flight.
__launch_bounds__(256, 4)
__global__ void scanA_k(const float* __restrict__ d1, const float* __restrict__ d2,
                        Ws* __restrict__ ws) {
    const int m = blockIdx.x >> 10;
    const int wave = threadIdx.x >> 6, lane = threadIdx.x & 63;
    const int v = ((blockIdx.x & 1023) << 2) + wave;
    const float4* __restrict__ row4 = (const float4*)((m ? d2 : d1) + (size_t)v * N);

    float4 w[16];
    #pragma unroll
    for (int j = 0; j < 16; ++j) w[j] = row4[lane + 64 * j];
    asm volatile("" ::: "memory");          // pin all 16 loads before consume

    const u32 uv = (u32)v;
    u64 bmin = INFK;
    #pragma unroll
    for (int j = 0; j < 16; ++j) {
        const u32 c0 = (u32)(4 * (lane + 64 * j));
        if (c0 + 0 != uv) bmin = umin64(bmin, (((u64)__float_as_uint(w[j].x)) << 12) | (c0 + 0));
        if (c0 + 1 != uv) bmin = umin64(bmin, (((u64)__float_as_uint(w[j].y)) << 12) | (c0 + 1));
        if (c0 + 2 != uv) bmin = umin64(bmin, (((u64)__float_as_uint(w[j].z)) << 12) | (c0 + 2));
        if (c0 + 3 != uv) bmin = umin64(bmin, (((u64)__float_as_uint(w[j].w)) << 12) | (c0 + 3));
    }
    ws->bmw[m][(size_t)v * 64 + lane] = (u32)(bmin >> 12);
    ws->bmc[m][(size_t)v * 64 + lane] = (u16)(bmin & 0xFFFu);

    u64 rowmin = bmin;
    #pragma unroll
    for (int off = 1; off <= 32; off <<= 1)
        rowmin = umin64(rowmin, shfl_xor_u64(rowmin, off));

    if (lane == 0) {
        u32 u  = (u32)rowmin & 0xFFFu;
        u64 wb = rowmin >> 12;
        u32 lo = min(uv, u), hi = max(uv, u);
        ws->best[m][0][v] = ((u64)13 << 56) | (wb << 24) | ((u64)lo << 12) | (u64)hi;
    }
}

// ---- dispatch r (r=1..12): replicated hook_{r-1} + scan round r ----
__launch_bounds__(256, 8)
__global__ void round_k(const float* __restrict__ d1, const float* __restrict__ d2,
                        Ws* __restrict__ ws, int r) {
    const int m = blockIdx.x >> 10;
    const int b = blockIdx.x & 1023;
    if (r > 1 && ws->ncomp[m] <= 1u) return;       // uniform per block

    const int tid = threadIdx.x, wave = tid >> 6, lane = tid & 63;
    const u32* __restrict__ cmP = ws->comp[m][(r - 1) & 1];   // valid for r>=2
    u32* __restrict__ cmC = ws->comp[m][r & 1];
    const u64* __restrict__ bprev = ws->best[m][(r - 1) & 1];
    u64* __restrict__ bcur = ws->best[m][r & 1];
    const u64 tagPrev = (u64)(14 - r);             // 13-(r-1), top byte
    const u64 tagCur  = ((u64)(13 - r)) << 56;

    __shared__ u32 nxt[N];                         // 16 KB
    __shared__ u32 red[4];

    // A: raw hooks (roots hook toward other endpoint's component)
    #pragma unroll
    for (int k = 0; k < 16; ++k) {
        int i = tid + k * 256;
        u32 ci = (r == 1) ? (u32)i : cmP[i];
        u32 x = (u32)i;
        if (ci == (u32)i) {
            u64 g = bprev[i];
            if ((g >> 56) == tagPrev) {
                u32 lo = (u32)(g >> 12) & 0xFFFu, hi = (u32)g & 0xFFFu;
                u32 cl = (r == 1) ? lo : cmP[lo];
                u32 ch = (r == 1) ? hi : cmP[hi];
                x = (cl == (u32)i) ? ch : cl;
            }
        }
        nxt[i] = x;
    }
    __syncthreads();

    // B: in-place 2-cycle resolve. Only the smaller mutual partner writes
    // (its own slot -> self), which cannot create/destroy the value another
    // root's mutuality check looks for — race-safe. Block 0 records edges.
    #pragma unroll
    for (int k = 0; k < 16; ++k) {
        int i = tid + k * 256;
        u32 ci = (r == 1) ? (u32)i : cmP[i];
        if (ci == (u32)i) {
            u32 o = nxt[i];
            bool dying = false;
            if (o != (u32)i) {
                bool mutual = (nxt[o] == (u32)i);
                bool survive = mutual && ((u32)i < o);
                if (survive) nxt[i] = (u32)i; else dying = true;
            }
            if (b == 0) {
                if (dying)        ws->edges[m][i] = (u32)(bprev[i] & 0xFFFFFFu);
                else if (r == 1)  ws->edges[m][i] = ((u32)i << 12) | (u32)i;  // sentinel
            }
        }
    }
    __syncthreads();

    // C: pointer jumping, in place (benign races; 12 steps cover depth 4096)
    for (int s = 0; s < 12; ++s) {
        #pragma unroll
        for (int k = 0; k < 16; ++k) {
            int i = tid + k * 256;
            nxt[i] = nxt[nxt[i]];
        }
        __syncthreads();
    }

    // D: count surviving roots (all blocks need it to decide scan-skip)
    u32 cnt = 0;
    #pragma unroll
    for (int k = 0; k < 16; ++k) {
        int i = tid + k * 256;
        u32 ci = (r == 1) ? (u32)i : cmP[i];
        if (ci == (u32)i && nxt[i] == (u32)i) cnt++;
    }
    #pragma unroll
    for (int off = 32; off >= 1; off >>= 1) cnt += (u32)__shfl_down((int)cnt, off, 64);
    if (lane == 0) red[wave] = cnt;
    __syncthreads();
    const u32 total = red[0] + red[1] + red[2] + red[3];

    // E: block 0 materializes comp_r (other parity) + ncomp for next dispatch
    if (b == 0) {
        #pragma unroll
        for (int k = 0; k < 16; ++k) {
            int i = tid + k * 256;
            u32 ci = (r == 1) ? (u32)i : cmP[i];
            cmC[i] = nxt[ci];
        }
        if (tid == 0) ws->ncomp[m] = total;
    }

    if (total <= 1u || r == NROUNDS) return;       // uniform

    // ---- scan phase: bound-table pruned, one wave per row, lane = block ----
    const int v = (b << 2) + wave;
    const float* __restrict__ dm = m ? d2 : d1;
    u32* __restrict__ bmwRow = ws->bmw[m] + (size_t)v * 64;
    u16* __restrict__ bmcRow = ws->bmc[m] + (size_t)v * 64;
    const u32 cvP = (r == 1) ? (u32)v : cmP[v];
    const u32 cv = nxt[cvP];

    u32 bw = bmwRow[lane];
    u32 bc = (u32)bmcRow[lane];
    u64 key = (bw == 0xFFFFFFFFu) ? INFK : (((u64)bw << 12) | bc);
    bool cross = false;
    if (key != INFK) {
        u32 cp = (r == 1) ? bc : cmP[bc];
        cross = (nxt[cp] != cv);
    }
    u64 kb = cross ? key : INFK;                   // exact cross candidates
    #pragma unroll
    for (int off = 1; off <= 32; off <<= 1)
        kb = umin64(kb, shfl_xor_u64(kb, off));

    const bool need = (!cross) && (key < kb);      // intra bound undercuts
    u64 nm = INFK;
    if (need) {
        const float4* __restrict__ row4 = (const float4*)(dm + (size_t)v * N);
        const uint4*  __restrict__ c4   = (const uint4*)cmP;
        #pragma unroll
        for (int j = 0; j < 16; ++j) {
            const int c = lane + 64 * j;
            float4 w = row4[c];
            const u32 c0 = (u32)(4 * c);
            u32 p0, p1, p2, p3;
            if (r == 1) { p0 = c0; p1 = c0 + 1; p2 = c0 + 2; p3 = c0 + 3; }
            else { uint4 cu = c4[c]; p0 = cu.x; p1 = cu.y; p2 = cu.z; p3 = cu.w; }
            if (nxt[p0] != cv) nm = umin64(nm, (((u64)__float_as_uint(w.x)) << 12) | (c0 + 0));
            if (nxt[p1] != cv) nm = umin64(nm, (((u64)__float_as_uint(w.y)) << 12) | (c0 + 1));
            if (nxt[p2] != cv) nm = umin64(nm, (((u64)__float_as_uint(w.z)) << 12) | (c0 + 2));
            if (nxt[p3] != cv) nm = umin64(nm, (((u64)__float_as_uint(w.w)) << 12) | (c0 + 3));
        }
        bmwRow[lane] = (nm == INFK) ? 0xFFFFFFFFu : (u32)(nm >> 12);
        bmcRow[lane] = (u16)(nm & 0xFFFu);
    }
    u64 kb2 = need ? nm : INFK;
    #pragma unroll
    for (int off = 1; off <= 32; off <<= 1)
        kb2 = umin64(kb2, shfl_xor_u64(kb2, off));

    u64 fin = umin64(kb, kb2);
    if (lane == 0 && fin != INFK) {
        u32 u  = (u32)fin & 0xFFFu;
        u64 wb = fin >> 12;
        u32 lo = min((u32)v, u), hi = max((u32)v, u);
        u64 g  = tagCur | (wb << 24) | ((u64)lo << 12) | (u64)hi;
        if (g < bcur[cv])                          // tagged: stale always loses
            atomicMin(&bcur[cv], g);
    }
}

__launch_bounds__(256, 1)
__global__ void epi_k(const float* __restrict__ d1, const float* __restrict__ d2,
                      Ws* __restrict__ ws, float* __restrict__ out) {
    const int m = blockIdx.x, tid = threadIdx.x;
    float acc = 0.f;
    for (int i = tid; i < N; i += 256) {
        u32 pk = ws->edges[m][i];
        u32 lo = (pk >> 12) & 0xFFFu, hi = pk & 0xFFFu;
        size_t off = (size_t)lo * N + hi;
        float df = d1[off] - d2[off];     // diagonal sentinel -> 0
        acc += df * df;
    }
    #pragma unroll
    for (int off = 32; off >= 1; off >>= 1) acc += __shfl_down(acc, off, 64);
    __shared__ float part[4];
    const int lane = tid & 63, wave = tid >> 6;
    if (lane == 0) part[wave] = acc;
    __syncthreads();
    if (tid == 0) atomicAdd(out, part[0] + part[1] + part[2] + part[3]);
}

extern "C" void kernel_launch(void* const* d_in, const int* in_sizes, int n_in,
                              void* d_out, int out_size, void* d_ws, size_t ws_size,
                              hipStream_t stream) {
    (void)in_sizes; (void)n_in; (void)out_size; (void)ws_size;
    const float* d1 = (const float*)d_in[0];
    const float* d2 = (const float*)d_in[1];
    float* out = (float*)d_out;
    Ws* ws = (Ws*)d_ws;   // ~3.4 MB scratch

    hipMemsetAsync(d_out, 0, sizeof(float), stream);
    scanA_k<<<dim3(2048), dim3(256), 0, stream>>>(d1, d2, ws);
    for (int r = 1; r <= NROUNDS; ++r)
        round_k<<<dim3(2048), dim3(256), 0, stream>>>(d1, d2, ws, r);
    epi_k<<<dim3(2), dim3(256), 0, stream>>>(d1, d2, ws, out);
}

// Round 11
// 262.661 us; speedup vs baseline: 2.2819x; 2.2819x over previous
//
#include <hip/hip_runtime.h>
#include <stdint.h>

// TopoSignature via parallel Boruvka MST. Round 11: r9 structure (proven
// 282 us) minus two dispatches and with cheaper hooks.
//  - init_k folded into scanA_k (lane0/row writes comp=v, edges=diag;
//    blocks 0/1024 write ncomp=N).
//  - epi_k fused into the final hook_k (fin flag; runs even when dead).
//  - hook pointer-jumping early-exits via __syncthreads_or (typ. depth <=4).
// Lessons kept: kernel boundary = the only cheap device-wide barrier (r8:
// threadfence ticket ~50-270us/round; r10: replicated hook = 94 MB re-reads
// + 7.5M LDS conflicts). scanA pinned at ~2.9 TB/s across 3 experiments —
// at its pattern ceiling; left alone.

#define N        4096
#define NROUNDS  12

typedef unsigned long long u64;
typedef uint32_t u32;

#define INFK (~0ull)

struct Ws {
    u64 best[2][N];      // per-component min outgoing edge key: (wbits<<24)|(lo<<12)|hi
    u32 comp[2][N];      // vertex -> component root label
    u32 edges[2][N];     // edge slot per vertex, (lo<<12)|hi; (i<<12)|i = none
    u32 ncomp[2];
    u32 pad[14];
    u64 bm[2][N * 64];   // per-row per-lane-block bound keys: (wbits<<12)|col ; 4 MB
};

__device__ __forceinline__ u64 umin64(u64 a, u64 b) { return a < b ? a : b; }

__device__ __forceinline__ u64 shfl_xor_u64(u64 x, int off) {
    u32 lo = (u32)x, hi = (u32)(x >> 32);
    lo = (u32)__shfl_xor((int)lo, off, 64);
    hi = (u32)__shfl_xor((int)hi, off, 64);
    return ((u64)hi << 32) | lo;
}

// ---- round 1 full scan + state init. One wave per row; lane-private block
// minima (block L = cols ≡ [4L,4L+4) mod 256). ----
__launch_bounds__(256, 8)
__global__ void scanA_k(const float* __restrict__ d1, const float* __restrict__ d2,
                        Ws* __restrict__ ws) {
    const int m = blockIdx.x >> 10;
    const int wave = threadIdx.x >> 6, lane = threadIdx.x & 63;
    const int v = ((blockIdx.x & 1023) << 2) + wave;
    const float4* __restrict__ row4 = (const float4*)((m ? d2 : d1) + (size_t)v * N);

    const u32 uv = (u32)v;
    u64 bmin = INFK;
    #pragma unroll
    for (int j = 0; j < 16; ++j) {
        const int c = lane + 64 * j;
        float4 w = row4[c];
        const u32 c0 = (u32)(4 * c);
        if (c0 + 0 != uv) bmin = umin64(bmin, (((u64)__float_as_uint(w.x)) << 12) | (c0 + 0));
        if (c0 + 1 != uv) bmin = umin64(bmin, (((u64)__float_as_uint(w.y)) << 12) | (c0 + 1));
        if (c0 + 2 != uv) bmin = umin64(bmin, (((u64)__float_as_uint(w.z)) << 12) | (c0 + 2));
        if (c0 + 3 != uv) bmin = umin64(bmin, (((u64)__float_as_uint(w.w)) << 12) | (c0 + 3));
    }
    ws->bm[m][(size_t)v * 64 + lane] = bmin;      // coalesced 512 B store

    u64 rowmin = bmin;
    #pragma unroll
    for (int off = 1; off <= 32; off <<= 1)
        rowmin = umin64(rowmin, shfl_xor_u64(rowmin, off));

    if (lane == 0) {
        u32 u  = (u32)rowmin & 0xFFFu;
        u64 wb = rowmin >> 12;
        u32 lo = min(uv, u), hi = max(uv, u);
        ws->best[m][v]  = (wb << 24) | ((u64)lo << 12) | (u64)hi;  // comp==v, unique writer
        ws->comp[m][v]  = uv;                                       // init fold
        ws->edges[m][v] = (uv << 12) | uv;                          // diag sentinel
    }
    if (threadIdx.x == 0 && (blockIdx.x & 1023) == 0)
        ws->ncomp[m] = (u32)N;
}

// ---- rounds 2+: bound-table scan. One wave per row, lane = block. ----
__launch_bounds__(256, 8)
__global__ void scan2_k(const float* __restrict__ d1, const float* __restrict__ d2,
                        Ws* __restrict__ ws) {
    const int m = blockIdx.x >> 10;
    if (ws->ncomp[m] <= 1u) return;
    const int wave = threadIdx.x >> 6, lane = threadIdx.x & 63;
    const int v = ((blockIdx.x & 1023) << 2) + wave;

    const float* __restrict__ dm = m ? d2 : d1;
    const u32*   __restrict__ cm = ws->comp[m];
    u64* __restrict__ bmrow = ws->bm[m] + (size_t)v * 64;

    const u32 cv = cm[v];
    u64 key = bmrow[lane];
    bool cross = false;
    if (key != INFK) cross = (cm[(u32)key & 0xFFFu] != cv);

    // best cross candidate among stored block mins (exact entries)
    u64 kb = cross ? key : INFK;
    #pragma unroll
    for (int off = 1; off <= 32; off <<= 1)
        kb = umin64(kb, shfl_xor_u64(kb, off));

    // intra bound undercutting kb -> block may hide a smaller cross entry
    const bool need = (!cross) && (key < kb);
    u64 nm = INFK;
    if (need) {
        const float4* __restrict__ row4 = (const float4*)(dm + (size_t)v * N);
        const uint4*  __restrict__ c4   = (const uint4*)cm;
        #pragma unroll
        for (int j = 0; j < 16; ++j) {
            const int c = lane + 64 * j;
            float4 w = row4[c];
            uint4 cu = c4[c];
            u32 c0 = (u32)(4 * c);
            if (cu.x != cv) nm = umin64(nm, (((u64)__float_as_uint(w.x)) << 12) | (c0 + 0));
            if (cu.y != cv) nm = umin64(nm, (((u64)__float_as_uint(w.y)) << 12) | (c0 + 1));
            if (cu.z != cv) nm = umin64(nm, (((u64)__float_as_uint(w.z)) << 12) | (c0 + 2));
            if (cu.w != cv) nm = umin64(nm, (((u64)__float_as_uint(w.w)) << 12) | (c0 + 3));
        }
        bmrow[lane] = nm;    // tightened bound: block's current min-cross key
    }
    u64 kb2 = need ? nm : INFK;
    #pragma unroll
    for (int off = 1; off <= 32; off <<= 1)
        kb2 = umin64(kb2, shfl_xor_u64(kb2, off));

    u64 fin = umin64(kb, kb2);
    if (lane == 0 && fin != INFK) {
        u32 u  = (u32)fin & 0xFFFu;
        u64 wb = fin >> 12;
        u32 lo = min((u32)v, u), hi = max((u32)v, u);
        u64 g  = (wb << 24) | ((u64)lo << 12) | (u64)hi;
        if (g < ws->best[m][cv])
            atomicMin(&ws->best[m][cv], g);
    }
}

// ---- fallback full scan (ws too small for bound table) ----
__launch_bounds__(256, 8)
__global__ void scanF_k(const float* __restrict__ d1, const float* __restrict__ d2,
                        Ws* __restrict__ ws, int first) {
    const int m = blockIdx.x >> 10;
    if (!first && ws->ncomp[m] <= 1u) return;
    const int wave = threadIdx.x >> 6, lane = threadIdx.x & 63;
    const int v = ((blockIdx.x & 1023) << 2) + wave;
    const float* __restrict__ dm = m ? d2 : d1;
    const u32*   __restrict__ cm = ws->comp[m];
    const float4* __restrict__ row4 = (const float4*)(dm + (size_t)v * N);
    const uint4*  __restrict__ c4   = (const uint4*)cm;
    const u32 cv = first ? (u32)v : cm[v];
    u64 kmin = INFK;
    #pragma unroll
    for (int j = 0; j < 16; ++j) {
        const int c = lane + 64 * j;
        float4 w = row4[c];
        uint4 cu;
        if (!first) cu = c4[c];
        const u32 c0 = (u32)(4 * c);
        bool x0, x1, x2, x3;
        if (first) {
            x0 = (c0+0 != cv); x1 = (c0+1 != cv); x2 = (c0+2 != cv); x3 = (c0+3 != cv);
        } else {
            x0 = (cu.x != cv); x1 = (cu.y != cv); x2 = (cu.z != cv); x3 = (cu.w != cv);
        }
        if (x0) kmin = umin64(kmin, (((u64)__float_as_uint(w.x)) << 12) | (c0 + 0));
        if (x1) kmin = umin64(kmin, (((u64)__float_as_uint(w.y)) << 12) | (c0 + 1));
        if (x2) kmin = umin64(kmin, (((u64)__float_as_uint(w.z)) << 12) | (c0 + 2));
        if (x3) kmin = umin64(kmin, (((u64)__float_as_uint(w.w)) << 12) | (c0 + 3));
    }
    #pragma unroll
    for (int off = 1; off <= 32; off <<= 1)
        kmin = umin64(kmin, shfl_xor_u64(kmin, off));
    if (lane == 0 && kmin != INFK) {
        u32 u  = (u32)kmin & 0xFFFu;
        u64 wb = kmin >> 12;
        u32 lo = min((u32)v, u), hi = max((u32)v, u);
        u64 g  = (wb << 24) | ((u64)lo << 12) | (u64)hi;
        if (first) {
            ws->best[m][v]  = g;
            ws->comp[m][v]  = (u32)v;
            ws->edges[m][v] = ((u32)v << 12) | (u32)v;
        } else if (g < ws->best[m][cv]) {
            atomicMin(&ws->best[m][cv], g);
        }
    }
    if (first && threadIdx.x == 0 && (blockIdx.x & 1023) == 0)
        ws->ncomp[m] = (u32)N;
}

// ---- hook: resolve 2-cycles, record edges (slot = dying root id),
// pointer-jump (early exit), relabel, reset best. One 1024-thread block per
// matrix. fin: also run the fused epilogue (even on the dead path). ----
__launch_bounds__(1024, 1)
__global__ void hook_k(const float* __restrict__ d1, const float* __restrict__ d2,
                       Ws* __restrict__ ws, float* __restrict__ out, int fin) {
    const int m = blockIdx.x;
    const int tid = threadIdx.x;
    const int lane = tid & 63, wave = tid >> 6;

    __shared__ u32 compL[N];
    __shared__ u32 nxtA[N];
    __shared__ u32 nxtB[N];
    __shared__ u32 red[16];
    __shared__ float fpart[16];

    if (ws->ncomp[m] > 1u) {
        u32* __restrict__ gcomp = ws->comp[m];
        u64* __restrict__ best  = ws->best[m];

        {
            uint4* dst = (uint4*)compL;
            const uint4* src = (const uint4*)gcomp;
            if (tid < N / 4) dst[tid] = src[tid];
        }
        __syncthreads();

        bool isroot[4];
        u64  bkey[4];

        #pragma unroll
        for (int k = 0; k < 4; ++k) {
            int i = tid + k * 1024;
            u32 x = (u32)i;
            bool r = (compL[i] == (u32)i);
            isroot[k] = r;
            u64 g = 0;
            if (r) {
                g = best[i];
                u32 lo = (u32)(g >> 12) & 0xFFFu;
                u32 hi = (u32)g & 0xFFFu;
                u32 cl = compL[lo], ch = compL[hi];
                x = (cl == (u32)i) ? ch : cl;
            }
            bkey[k] = g;
            nxtA[i] = x;
        }
        __syncthreads();

        #pragma unroll
        for (int k = 0; k < 4; ++k) {
            int i = tid + k * 1024;
            u32 nn = (u32)i;
            if (isroot[k]) {
                u32 o = nxtA[i];
                bool mutual = (nxtA[o] == (u32)i);
                nn = (mutual && ((u32)i < o)) ? (u32)i : o;
                if (nn != (u32)i)
                    ws->edges[m][i] = (u32)(bkey[k] & 0xFFFFFFu);
            }
            nxtB[i] = nn;
        }
        __syncthreads();

        // pointer jumping with early exit (typical depth <= 4)
        for (int s = 0; s < 12; ++s) {
            u32 changed = 0;
            #pragma unroll
            for (int k = 0; k < 4; ++k) {
                int i = tid + k * 1024;
                u32 a = nxtB[i];
                u32 t = nxtB[a];
                if (t != a) changed = 1u;
                nxtB[i] = t;
            }
            if (!__syncthreads_or((int)changed)) break;
        }

        u32 cnt = 0;
        #pragma unroll
        for (int k = 0; k < 4; ++k) {
            int i = tid + k * 1024;
            if (isroot[k] && nxtB[i] == (u32)i) cnt++;
        }
        #pragma unroll
        for (int off = 32; off >= 1; off >>= 1) cnt += (u32)__shfl_down((int)cnt, off, 64);
        if (lane == 0) red[wave] = cnt;
        __syncthreads();

        #pragma unroll
        for (int k = 0; k < 4; ++k) {
            int i = tid + k * 1024;
            gcomp[i] = nxtB[compL[i]];
            if (isroot[k]) best[i] = INFK;
        }
        if (tid == 0) {
            u32 t = 0;
            #pragma unroll
            for (int w = 0; w < 16; ++w) t += red[w];
            ws->ncomp[m] = t;
        }
    }

    // ---- fused epilogue on the final round ----
    if (fin) {
        __syncthreads();
        float acc = 0.f;
        #pragma unroll
        for (int k = 0; k < 4; ++k) {
            int i = tid + k * 1024;
            u32 pk = ws->edges[m][i];
            u32 lo = (pk >> 12) & 0xFFFu, hi = pk & 0xFFFu;
            size_t off = (size_t)lo * N + hi;
            float df = d1[off] - d2[off];     // diagonal sentinel -> 0
            acc += df * df;
        }
        #pragma unroll
        for (int off = 32; off >= 1; off >>= 1) acc += __shfl_down(acc, off, 64);
        if (lane == 0) fpart[wave] = acc;
        __syncthreads();
        if (tid == 0) {
            float t = 0.f;
            #pragma unroll
            for (int w = 0; w < 16; ++w) t += fpart[w];
            atomicAdd(out, t);
        }
    }
}

extern "C" void kernel_launch(void* const* d_in, const int* in_sizes, int n_in,
                              void* d_out, int out_size, void* d_ws, size_t ws_size,
                              hipStream_t stream) {
    (void)in_sizes; (void)n_in; (void)out_size;
    const float* d1 = (const float*)d_in[0];
    const float* d2 = (const float*)d_in[1];
    float* out = (float*)d_out;
    Ws* ws = (Ws*)d_ws;
    const bool big = (ws_size >= sizeof(Ws));   // ~4.4 MB needed for bound table

    hipMemsetAsync(d_out, 0, sizeof(float), stream);
    for (int r = 0; r < NROUNDS; ++r) {
        if (big) {
            if (r == 0) scanA_k<<<dim3(2048), dim3(256), 0, stream>>>(d1, d2, ws);
            else        scan2_k<<<dim3(2048), dim3(256), 0, stream>>>(d1, d2, ws);
        } else {
            scanF_k<<<dim3(2048), dim3(256), 0, stream>>>(d1, d2, ws, r == 0 ? 1 : 0);
        }
        hook_k<<<dim3(2), dim3(1024), 0, stream>>>(d1, d2, ws, out, r == NROUNDS - 1 ? 1 : 0);
    }
}